// Round 3
// baseline (257.977 us; speedup 1.0000x reference)
//
#include <hip/hip_runtime.h>
#include <math.h>

#define N_NODES 200000
#define K_DEG 16
#define G_GRAPHS 4000
#define F_IN 25
#define EPSV 1e-5f

__device__ inline unsigned short f2bf(float f) {
    unsigned int u = __float_as_uint(f);
    u += 0x7fff + ((u >> 16) & 1);            // RNE
    return (unsigned short)(u >> 16);
}
__device__ inline float bf2f(unsigned short h) {
    return __uint_as_float(((unsigned int)h) << 16);
}

// ---------------------------------------------------------------------------
// prep: fold weights.  deg==16 for all nodes -> scalers identity; dst-side is
// linear and folds through the post-MLP:
//   h1 = relu( M1@[mean_c,min_c,max_c,std_c] + P1@x + bvp1 ),  P1=(Mmean+Mmin+Mmax)@Wd1
// Block 0: layer 1 -> C1 (16x100 = M1), P1 (16x25), bvp1.
// Block 1: layer 2 -> C2 (8x64 = M2),  P2 (8x16),  bvp2.
// ---------------------------------------------------------------------------
__global__ void prep(const float* __restrict__ w1_pre, const float* __restrict__ b1_pre,
                     const float* __restrict__ w1_post, const float* __restrict__ b1_post,
                     const float* __restrict__ w1_lin, const float* __restrict__ b1_lin,
                     const float* __restrict__ w2_pre, const float* __restrict__ b2_pre,
                     const float* __restrict__ w2_post, const float* __restrict__ b2_post,
                     const float* __restrict__ w2_lin, const float* __restrict__ b2_lin,
                     float* __restrict__ C1, float* __restrict__ bvp1, float* __restrict__ P1,
                     float* __restrict__ C2, float* __restrict__ bvp2, float* __restrict__ P2) {
    int tid = threadIdx.x;
    if (blockIdx.x == 0) {
        __shared__ float wp[16 * 300];
        __shared__ float wl[256];
        __shared__ float m1[1600];
        __shared__ float a1[400];
        for (int i = tid; i < 4800; i += 256) wp[i] = w1_post[i];
        for (int i = tid; i < 256; i += 256) wl[i] = w1_lin[i];
        __syncthreads();
        for (int i = tid; i < 1600; i += 256) {
            int o = i / 100, j = i % 100;
            float s = 0.f;
            for (int h = 0; h < 16; ++h)
                s += wl[o * 16 + h] * (wp[h * 300 + j] + wp[h * 300 + 100 + j] + wp[h * 300 + 200 + j]);
            m1[i] = s;
            C1[i] = s;
        }
        __syncthreads();
        for (int i = tid; i < 400; i += 256) {
            int o = i / 25, f = i % 25;
            a1[i] = m1[o * 100 + f] + m1[o * 100 + 25 + f] + m1[o * 100 + 50 + f];
        }
        __syncthreads();
        for (int i = tid; i < 400; i += 256) {
            int o = i / 25, k = i % 25;
            float s = 0.f;
            for (int f = 0; f < 25; ++f) s += a1[o * 25 + f] * w1_pre[f * 50 + k];
            P1[i] = s;
        }
        if (tid < 16) {
            float s = b1_lin[tid];
            for (int h = 0; h < 16; ++h) s += wl[tid * 16 + h] * b1_post[h];
            for (int f = 0; f < 25; ++f) s += a1[tid * 25 + f] * b1_pre[f];
            bvp1[tid] = s;
        }
    } else {
        __shared__ float wp[8 * 192];
        __shared__ float wl[64];
        __shared__ float m2[512];
        __shared__ float a2[128];
        for (int i = tid; i < 1536; i += 256) wp[i] = w2_post[i];
        if (tid < 64) wl[tid] = w2_lin[tid];
        __syncthreads();
        for (int i = tid; i < 512; i += 256) {
            int o = i / 64, j = i % 64;
            float s = 0.f;
            for (int h = 0; h < 8; ++h)
                s += wl[o * 8 + h] * (wp[h * 192 + j] + wp[h * 192 + 64 + j] + wp[h * 192 + 128 + j]);
            m2[i] = s;
            C2[i] = s;
        }
        __syncthreads();
        if (tid < 128) {
            int o = tid / 16, f = tid % 16;
            a2[tid] = m2[o * 64 + f] + m2[o * 64 + 16 + f] + m2[o * 64 + 32 + f];
        }
        __syncthreads();
        if (tid < 128) {
            int o = tid / 16, k = tid % 16;
            float s = 0.f;
            for (int f = 0; f < 16; ++f) s += a2[o * 16 + f] * w2_pre[f * 32 + k];
            P2[tid] = s;
        }
        if (tid < 8) {
            float s = b2_lin[tid];
            for (int h = 0; h < 8; ++h) s += wl[tid * 8 + h] * b2_post[h];
            for (int f = 0; f < 16; ++f) s += a2[tid * 16 + f] * b2_pre[f];
            bvp2[tid] = s;
        }
    }
}

// ---------------------------------------------------------------------------
// pre1: per 256-node tile: c1 = Ws1@x (bf16, 32-short rows) and d1 = P1@x (fp32).
// x row staged via LDS (coalesced), kept in registers; weights broadcast from LDS.
// ---------------------------------------------------------------------------
__global__ void __launch_bounds__(256) pre1(const float* __restrict__ x,
                                            const float* __restrict__ w1_pre,
                                            const float* __restrict__ P1,
                                            unsigned int* __restrict__ c1b_dw,
                                            float* __restrict__ d1) {
    __shared__ float xs[256 * 25];
    __shared__ float wls[25 * 25];
    __shared__ float pls[16 * 25];
    __shared__ unsigned int otile[256 * 17];   // stride-17 to dodge bank conflicts
    int tid = threadIdx.x;
    int base = blockIdx.x * 256;
    for (int i = tid; i < 6400; i += 256) {
        int g = base * 25 + i;
        xs[i] = (g < N_NODES * F_IN) ? x[g] : 0.f;
    }
    for (int i = tid; i < 625; i += 256) {
        int f = i / 25, k = i % 25;
        wls[i] = w1_pre[f * 50 + 25 + k];      // src half
    }
    for (int i = tid; i < 400; i += 256) pls[i] = P1[i];
    __syncthreads();

    float xr[25];
#pragma unroll
    for (int k = 0; k < 25; ++k) xr[k] = xs[tid * 25 + k];

    // c1 = Ws1 @ x, packed bf16 pairs
    unsigned int pk[16];
#pragma unroll
    for (int j = 0; j < 16; ++j) pk[j] = 0;
#pragma unroll
    for (int f = 0; f < 25; ++f) {
        float s = 0.f;
#pragma unroll
        for (int k = 0; k < 25; ++k) s += wls[f * 25 + k] * xr[k];
        unsigned int b = f2bf(s);
        pk[f >> 1] |= (f & 1) ? (b << 16) : b;
    }
#pragma unroll
    for (int j = 0; j < 16; ++j) otile[tid * 17 + j] = pk[j];
    __syncthreads();
    for (int i = tid; i < 4096; i += 256) {
        int g = base * 16 + i;
        if (g < N_NODES * 16) c1b_dw[g] = otile[(i >> 4) * 17 + (i & 15)];
    }
    __syncthreads();

    // d1 = P1 @ x
    float* ftile = (float*)otile;
#pragma unroll
    for (int o = 0; o < 16; ++o) {
        float s = 0.f;
#pragma unroll
        for (int k = 0; k < 25; ++k) s += pls[o * 25 + k] * xr[k];
        ftile[tid * 17 + o] = s;
    }
    __syncthreads();
    for (int i = tid; i < 4096; i += 256) {
        int g = base * 16 + i;
        if (g < N_NODES * 16) d1[g] = ftile[(i >> 4) * 17 + (i & 15)];
    }
}

// ---------------------------------------------------------------------------
// agg1: gather c1 (bf16 rows), aggregate, h1 = relu(M1@agg + d1 + bvp1) in LDS,
// then epilogue: c2 = Ws2@h1 (bf16) and d2 = P2@h1 (fp32).  h1 never hits global.
// ---------------------------------------------------------------------------
#define A1_NPB 8
__global__ void __launch_bounds__(256) agg1(const unsigned short* __restrict__ c1b,
                                            const int* __restrict__ src,
                                            const float* __restrict__ d1,
                                            const float* __restrict__ C1,
                                            const float* __restrict__ bvp1,
                                            const float* __restrict__ w2_pre,
                                            const float* __restrict__ P2,
                                            unsigned short* __restrict__ c2b,
                                            float* __restrict__ d2) {
    __shared__ float cs[16 * 100];
    __shared__ float aggs[A1_NPB * 100];
    __shared__ float h1s[A1_NPB * 17];
    __shared__ float ws2[16 * 17];
    __shared__ float p2s[8 * 17];
    __shared__ float bvs[16];
    int tid = threadIdx.x;
    for (int i = tid; i < 1600; i += 256) cs[i] = C1[i];
    if (tid < 256) {
        int f = tid >> 4, k = tid & 15;
        ws2[f * 17 + k] = w2_pre[f * 32 + 16 + k];
    }
    if (tid < 128) {
        int o = tid >> 4, k = tid & 15;
        p2s[o * 17 + k] = P2[tid];
    }
    if (tid < 16) bvs[tid] = bvp1[tid];
    __syncthreads();

    int group = tid >> 5;
    int lane  = tid & 31;
    int n = blockIdx.x * A1_NPB + group;
    if (lane < F_IN) {
        const int* sp = src + n * K_DEG;
        int idx[K_DEG];
#pragma unroll
        for (int e = 0; e < K_DEG; ++e) idx[e] = sp[e];
        float v[K_DEG];
#pragma unroll
        for (int e = 0; e < K_DEG; ++e) v[e] = bf2f(c1b[idx[e] * 32 + lane]);
        float s = 0.f, sq = 0.f, mn = 1e30f, mx = -1e30f;
#pragma unroll
        for (int e = 0; e < K_DEG; ++e) {
            float m = v[e];
            s += m; sq += m * m; mn = fminf(mn, m); mx = fmaxf(mx, m);
        }
        float mean = s * (1.f / 16.f);
        float var  = sq * (1.f / 16.f) - mean * mean;
        float sd   = sqrtf(fmaxf(var, 0.f) + EPSV);
        aggs[group * 100 + lane]      = mean;
        aggs[group * 100 + 25 + lane] = mn;
        aggs[group * 100 + 50 + lane] = mx;
        aggs[group * 100 + 75 + lane] = sd;
    }
    __syncthreads();

    if (tid < A1_NPB * 16) {
        int nl = tid >> 4, o = tid & 15;
        int nn = blockIdx.x * A1_NPB + nl;
        float s = bvs[o] + d1[nn * 16 + o];
        const float4* c4 = (const float4*)(cs + o * 100);
        const float4* a4 = (const float4*)(aggs + nl * 100);
#pragma unroll
        for (int j = 0; j < 25; ++j) {
            float4 cv = c4[j], av = a4[j];
            s += cv.x * av.x + cv.y * av.y + cv.z * av.z + cv.w * av.w;
        }
        h1s[nl * 17 + o] = fmaxf(s, 0.f);
    }
    __syncthreads();

    if (tid < A1_NPB * 16) {          // c2 = Ws2 @ h1
        int nl = tid >> 4, f = tid & 15;
        int nn = blockIdx.x * A1_NPB + nl;
        const float* hr = h1s + nl * 17;
        float s = 0.f;
#pragma unroll
        for (int k = 0; k < 16; ++k) s += ws2[f * 17 + k] * hr[k];
        c2b[nn * 16 + f] = f2bf(s);
    } else if (tid < A1_NPB * 16 + A1_NPB * 8) {   // d2 = P2 @ h1
        int t = tid - A1_NPB * 16;
        int nl = t >> 3, o = t & 7;
        int nn = blockIdx.x * A1_NPB + nl;
        const float* hr = h1s + nl * 17;
        float s = 0.f;
#pragma unroll
        for (int k = 0; k < 16; ++k) s += p2s[o * 17 + k] * hr[k];
        d2[nn * 8 + o] = s;
    }
}

// ---------------------------------------------------------------------------
// agg2: gather c2 (bf16 16-short rows), aggregate, h2 = relu(M2@agg + d2 + bvp2).
// ---------------------------------------------------------------------------
#define A2_NPB 16
__global__ void __launch_bounds__(256) agg2(const unsigned short* __restrict__ c2b,
                                            const int* __restrict__ src,
                                            const float* __restrict__ d2,
                                            const float* __restrict__ C2,
                                            const float* __restrict__ bvp2,
                                            float* __restrict__ h2) {
    __shared__ float cs[8 * 68];
    __shared__ float ag[A2_NPB * 68];
    __shared__ float bvs[8];
    int tid = threadIdx.x;
    for (int i = tid; i < 512; i += 256) cs[(i >> 6) * 68 + (i & 63)] = C2[i];
    if (tid < 8) bvs[tid] = bvp2[tid];
    __syncthreads();

    int group = tid >> 4;
    int lane  = tid & 15;
    int n = blockIdx.x * A2_NPB + group;
    {
        const int* sp = src + n * K_DEG;
        int idx[K_DEG];
#pragma unroll
        for (int e = 0; e < K_DEG; ++e) idx[e] = sp[e];
        float v[K_DEG];
#pragma unroll
        for (int e = 0; e < K_DEG; ++e) v[e] = bf2f(c2b[idx[e] * 16 + lane]);
        float s = 0.f, sq = 0.f, mn = 1e30f, mx = -1e30f;
#pragma unroll
        for (int e = 0; e < K_DEG; ++e) {
            float m = v[e];
            s += m; sq += m * m; mn = fminf(mn, m); mx = fmaxf(mx, m);
        }
        float mean = s * (1.f / 16.f);
        float var  = sq * (1.f / 16.f) - mean * mean;
        float sd   = sqrtf(fmaxf(var, 0.f) + EPSV);
        ag[group * 68 + lane]      = mean;
        ag[group * 68 + 16 + lane] = mn;
        ag[group * 68 + 32 + lane] = mx;
        ag[group * 68 + 48 + lane] = sd;
    }
    __syncthreads();

    if (tid < A2_NPB * 8) {
        int nl = tid >> 3, o = tid & 7;
        int nn = blockIdx.x * A2_NPB + nl;
        float s = bvs[o] + d2[nn * 8 + o];
        const float4* c4 = (const float4*)(cs + o * 68);
        const float4* a4 = (const float4*)(ag + nl * 68);
#pragma unroll
        for (int j = 0; j < 16; ++j) {
            float4 cv = c4[j], av = a4[j];
            s += cv.x * av.x + cv.y * av.y + cv.z * av.z + cv.w * av.w;
        }
        h2[nn * 8 + o] = fmaxf(s, 0.f);
    }
}

// ---------------------------------------------------------------------------
// pool (50 contiguous nodes / graph) + fc + log_softmax.  1 wave per graph.
// ---------------------------------------------------------------------------
__global__ void pool_fc(const float* __restrict__ h2, const float* __restrict__ fc_w,
                        const float* __restrict__ fc_b, float* __restrict__ out) {
    int wave = threadIdx.x >> 6;
    int lane = threadIdx.x & 63;
    int g = blockIdx.x * 4 + wave;
    float s0 = 0.f, s1 = 0.f;
    if (lane < 50) {
        const float* hr = h2 + (g * 50 + lane) * 8;
        float v[8];
#pragma unroll
        for (int o = 0; o < 8; ++o) v[o] = hr[o];
#pragma unroll
        for (int o = 0; o < 8; ++o) { s0 += fc_w[o] * v[o]; s1 += fc_w[8 + o] * v[o]; }
    }
#pragma unroll
    for (int off = 32; off > 0; off >>= 1) {
        s0 += __shfl_down(s0, off);
        s1 += __shfl_down(s1, off);
    }
    if (lane == 0) {
        float l0 = s0 + fc_b[0], l1 = s1 + fc_b[1];
        float m = fmaxf(l0, l1);
        float lse = m + logf(expf(l0 - m) + expf(l1 - m));
        out[g * 2]     = l0 - lse;
        out[g * 2 + 1] = l1 - lse;
    }
}

extern "C" void kernel_launch(void* const* d_in, const int* in_sizes, int n_in,
                              void* d_out, int out_size, void* d_ws, size_t ws_size,
                              hipStream_t stream) {
    const float* x       = (const float*)d_in[0];
    const int*   eidx    = (const int*)d_in[1];   // [2][E]; row 0 = src
    const float* w1_pre  = (const float*)d_in[3];
    const float* b1_pre  = (const float*)d_in[4];
    const float* w1_post = (const float*)d_in[5];
    const float* b1_post = (const float*)d_in[6];
    const float* w1_lin  = (const float*)d_in[7];
    const float* b1_lin  = (const float*)d_in[8];
    const float* w2_pre  = (const float*)d_in[9];
    const float* b2_pre  = (const float*)d_in[10];
    const float* w2_post = (const float*)d_in[11];
    const float* b2_post = (const float*)d_in[12];
    const float* w2_lin  = (const float*)d_in[13];
    const float* b2_lin  = (const float*)d_in[14];
    const float* fc_w    = (const float*)d_in[15];
    const float* fc_b    = (const float*)d_in[16];
    float* out = (float*)d_out;
    const int* src = eidx;

    char* ws = (char*)d_ws;
    unsigned short* c1b = (unsigned short*)ws;                // N*32*2  = 12.8 MB
    unsigned short* c2b = (unsigned short*)(ws + 12800000);   // N*16*2  =  6.4 MB
    float* d1  = (float*)(ws + 19200000);                     // N*16*4  = 12.8 MB
    float* d2  = (float*)(ws + 32000000);                     // N*8*4   =  6.4 MB
    float* h2  = (float*)(ws + 38400000);                     // N*8*4   =  6.4 MB
    float* C1   = (float*)(ws + 44800000);                    // 1600
    float* bvp1 = C1 + 1600;                                  // 16
    float* P1   = bvp1 + 16;                                  // 400
    float* C2   = P1 + 400;                                   // 512
    float* bvp2 = C2 + 512;                                   // 8
    float* P2   = bvp2 + 8;                                   // 128

    prep<<<2, 256, 0, stream>>>(w1_pre, b1_pre, w1_post, b1_post, w1_lin, b1_lin,
                                w2_pre, b2_pre, w2_post, b2_post, w2_lin, b2_lin,
                                C1, bvp1, P1, C2, bvp2, P2);
    pre1<<<(N_NODES + 255) / 256, 256, 0, stream>>>(x, w1_pre, P1, (unsigned int*)c1b, d1);
    agg1<<<N_NODES / A1_NPB, 256, 0, stream>>>(c1b, src, d1, C1, bvp1, w2_pre, P2, c2b, d2);
    agg2<<<N_NODES / A2_NPB, 256, 0, stream>>>(c2b, src, d2, C2, bvp2, h2);
    pool_fc<<<G_GRAPHS / 4, 256, 0, stream>>>(h2, fc_w, fc_b, out);
}

// Round 4
// 241.926 us; speedup vs baseline: 1.0663x; 1.0663x over previous
//
#include <hip/hip_runtime.h>
#include <math.h>

#define N_NODES 200000
#define K_DEG 16
#define G_GRAPHS 4000
#define F_IN 25
#define EPSV 1e-5f

__device__ inline unsigned short f2bf(float f) {
    unsigned int u = __float_as_uint(f);
    u += 0x7fff + ((u >> 16) & 1);            // RNE
    return (unsigned short)(u >> 16);
}
__device__ inline float bf2f(unsigned short h) {
    return __uint_as_float(((unsigned int)h) << 16);
}

// ---------------------------------------------------------------------------
// prep: fold weights (deg==16 -> scalers identity, dst-side linear & foldable).
//   C1ext: 16 x 108 padded [mean25|0|min25|0|max25|0|std25|0|pad4], zeros in pads
//   P1: 16x25 (dst-side fold onto raw x), bvp1: 16
//   C2p: 8 x 68 padded [64|0000], P2: 8x16, bvp2: 8
// Single block, layer 2 reuses LDS buffers.
// ---------------------------------------------------------------------------
__global__ void prep(const float* __restrict__ w1_pre, const float* __restrict__ b1_pre,
                     const float* __restrict__ w1_post, const float* __restrict__ b1_post,
                     const float* __restrict__ w1_lin, const float* __restrict__ b1_lin,
                     const float* __restrict__ w2_pre, const float* __restrict__ b2_pre,
                     const float* __restrict__ w2_post, const float* __restrict__ b2_post,
                     const float* __restrict__ w2_lin, const float* __restrict__ b2_lin,
                     float* __restrict__ C1ext, float* __restrict__ bvp1, float* __restrict__ P1,
                     float* __restrict__ C2p, float* __restrict__ bvp2, float* __restrict__ P2) {
    __shared__ float wp[4800];
    __shared__ float wl[256];
    __shared__ float mm[1600];
    __shared__ float aa[400];
    int tid = threadIdx.x;
    // ---- layer 1 ----
    for (int i = tid; i < 4800; i += 256) wp[i] = w1_post[i];
    if (tid < 256) wl[tid] = w1_lin[tid];
    __syncthreads();
    for (int i = tid; i < 1600; i += 256) {
        int o = i / 100, j = i % 100;
        float s = 0.f;
        for (int h = 0; h < 16; ++h)
            s += wl[o * 16 + h] * (wp[h * 300 + j] + wp[h * 300 + 100 + j] + wp[h * 300 + 200 + j]);
        mm[i] = s;
    }
    __syncthreads();
    for (int i = tid; i < 400; i += 256) {
        int o = i / 25, f = i % 25;
        aa[i] = mm[o * 100 + f] + mm[o * 100 + 25 + f] + mm[o * 100 + 50 + f];
    }
    __syncthreads();
    for (int i = tid; i < 1728; i += 256) {            // padded C1ext
        int o = i / 108, c = i % 108;
        int st = c / 26, f = c % 26;
        C1ext[i] = (c < 104 && f < 25) ? mm[o * 100 + st * 25 + f] : 0.f;
    }
    for (int i = tid; i < 400; i += 256) {             // P1 = A1 @ Wd1
        int o = i / 25, k = i % 25;
        float s = 0.f;
        for (int f = 0; f < 25; ++f) s += aa[o * 25 + f] * w1_pre[f * 50 + k];
        P1[i] = s;
    }
    if (tid < 16) {
        float s = b1_lin[tid];
        for (int h = 0; h < 16; ++h) s += wl[tid * 16 + h] * b1_post[h];
        for (int f = 0; f < 25; ++f) s += aa[tid * 25 + f] * b1_pre[f];
        bvp1[tid] = s;
    }
    __syncthreads();
    // ---- layer 2 (reuse buffers) ----
    for (int i = tid; i < 1536; i += 256) wp[i] = w2_post[i];
    if (tid < 64) wl[tid] = w2_lin[tid];
    __syncthreads();
    for (int i = tid; i < 512; i += 256) {
        int o = i / 64, j = i % 64;
        float s = 0.f;
        for (int h = 0; h < 8; ++h)
            s += wl[o * 8 + h] * (wp[h * 192 + j] + wp[h * 192 + 64 + j] + wp[h * 192 + 128 + j]);
        mm[i] = s;
    }
    __syncthreads();
    if (tid < 128) {
        int o = tid / 16, f = tid % 16;
        aa[tid] = mm[o * 64 + f] + mm[o * 64 + 16 + f] + mm[o * 64 + 32 + f];
    }
    __syncthreads();
    for (int i = tid; i < 544; i += 256) {
        int o = i / 68, c = i % 68;
        C2p[i] = (c < 64) ? mm[o * 64 + c] : 0.f;
    }
    if (tid < 128) {
        int o = tid / 16, k = tid % 16;
        float s = 0.f;
        for (int f = 0; f < 16; ++f) s += aa[o * 16 + f] * w2_pre[f * 32 + k];
        P2[tid] = s;
    }
    if (tid < 8) {
        float s = b2_lin[tid];
        for (int h = 0; h < 8; ++h) s += wl[tid * 8 + h] * b2_post[h];
        for (int f = 0; f < 16; ++f) s += aa[tid * 16 + f] * b2_pre[f];
        bvp2[tid] = s;
    }
}

// ---------------------------------------------------------------------------
// pre1: per 256-node tile: c1 = Ws1@x (bf16 pairs, 16-uint rows) and d1 = P1@x.
// ---------------------------------------------------------------------------
__global__ void __launch_bounds__(256) pre1(const float* __restrict__ x,
                                            const float* __restrict__ w1_pre,
                                            const float* __restrict__ P1,
                                            unsigned int* __restrict__ c1b_dw,
                                            float* __restrict__ d1) {
    __shared__ float xs[256 * 25];
    __shared__ float wls[25 * 25];
    __shared__ float pls[16 * 25];
    __shared__ unsigned int otile[256 * 17];
    int tid = threadIdx.x;
    int base = blockIdx.x * 256;
    for (int i = tid; i < 6400; i += 256) {
        int g = base * 25 + i;
        xs[i] = (g < N_NODES * F_IN) ? x[g] : 0.f;
    }
    for (int i = tid; i < 625; i += 256) {
        int f = i / 25, k = i % 25;
        wls[i] = w1_pre[f * 50 + 25 + k];
    }
    for (int i = tid; i < 400; i += 256) pls[i] = P1[i];
    __syncthreads();

    float xr[25];
#pragma unroll
    for (int k = 0; k < 25; ++k) xr[k] = xs[tid * 25 + k];

    unsigned int pk[16];
#pragma unroll
    for (int j = 0; j < 16; ++j) pk[j] = 0;
#pragma unroll
    for (int f = 0; f < 25; ++f) {
        float s = 0.f;
#pragma unroll
        for (int k = 0; k < 25; ++k) s += wls[f * 25 + k] * xr[k];
        unsigned int b = f2bf(s);
        pk[f >> 1] |= (f & 1) ? (b << 16) : b;
    }
#pragma unroll
    for (int j = 0; j < 16; ++j) otile[tid * 17 + j] = pk[j];
    __syncthreads();
    for (int i = tid; i < 4096; i += 256) {
        int g = base * 16 + i;
        if (g < N_NODES * 16) c1b_dw[g] = otile[(i >> 4) * 17 + (i & 15)];
    }
    __syncthreads();

    float* ftile = (float*)otile;
#pragma unroll
    for (int o = 0; o < 16; ++o) {
        float s = 0.f;
#pragma unroll
        for (int k = 0; k < 25; ++k) s += pls[o * 25 + k] * xr[k];
        ftile[tid * 17 + o] = s;
    }
    __syncthreads();
    for (int i = tid; i < 4096; i += 256) {
        int g = base * 16 + i;
        if (g < N_NODES * 16) d1[g] = ftile[(i >> 4) * 17 + (i & 15)];
    }
}

// ---------------------------------------------------------------------------
// agg1: 16 lanes/node, 16 nodes/block.  uint gathers (2 feats/lane), coalesced
// LDS-staged edge indices.  h1 in LDS, epilogue emits c2b (bf16) + d2.
// ---------------------------------------------------------------------------
__global__ void __launch_bounds__(256) agg1(const unsigned int* __restrict__ c1u,
                                            const int* __restrict__ src,
                                            const float* __restrict__ d1,
                                            const float* __restrict__ C1ext,
                                            const float* __restrict__ bvp1,
                                            const float* __restrict__ w2_pre,
                                            const float* __restrict__ P2,
                                            unsigned short* __restrict__ c2b,
                                            float* __restrict__ d2) {
    __shared__ float cs[16 * 108];
    __shared__ float aggs[16 * 108];
    __shared__ float h1s[16 * 17];
    __shared__ float ws2[16 * 17];
    __shared__ float p2s[8 * 17];
    __shared__ float bvs[16];
    __shared__ int idxs[256];
    int tid = threadIdx.x;
    for (int i = tid; i < 1728; i += 256) cs[i] = C1ext[i];
    {
        int f = tid >> 4, k = tid & 15;
        ws2[f * 17 + k] = w2_pre[f * 32 + 16 + k];
    }
    if (tid < 128) p2s[(tid >> 4) * 17 + (tid & 15)] = P2[tid];
    if (tid < 16) bvs[tid] = bvp1[tid];
    idxs[tid] = src[blockIdx.x * 256 + tid];
    __syncthreads();

    int g = tid >> 4;           // node-in-block
    int L = tid & 15;           // lane-in-node: feats 2L, 2L+1
    {
        int id[K_DEG];
#pragma unroll
        for (int e = 0; e < K_DEG; ++e) id[e] = idxs[g * 16 + e];
        unsigned int v[K_DEG];
#pragma unroll
        for (int e = 0; e < K_DEG; ++e) v[e] = c1u[id[e] * 16 + L];
        float s0 = 0.f, q0 = 0.f, n0 = 1e30f, x0 = -1e30f;
        float s1 = 0.f, q1 = 0.f, n1 = 1e30f, x1 = -1e30f;
#pragma unroll
        for (int e = 0; e < K_DEG; ++e) {
            float a = bf2f((unsigned short)(v[e] & 0xffff));
            float b = bf2f((unsigned short)(v[e] >> 16));
            s0 += a; q0 += a * a; n0 = fminf(n0, a); x0 = fmaxf(x0, a);
            s1 += b; q1 += b * b; n1 = fminf(n1, b); x1 = fmaxf(x1, b);
        }
        float me0 = s0 * (1.f / 16.f), me1 = s1 * (1.f / 16.f);
        float sd0 = sqrtf(fmaxf(q0 * (1.f / 16.f) - me0 * me0, 0.f) + EPSV);
        float sd1 = sqrtf(fmaxf(q1 * (1.f / 16.f) - me1 * me1, 0.f) + EPSV);
        if (L < 13) {
            float* r = aggs + g * 108 + 2 * L;
            *(float2*)(r)      = make_float2(me0, me1);
            *(float2*)(r + 26) = make_float2(n0, n1);
            *(float2*)(r + 52) = make_float2(x0, x1);
            *(float2*)(r + 78) = make_float2(sd0, sd1);
        } else if (L == 13) {
            *(float4*)(aggs + g * 108 + 104) = make_float4(0.f, 0.f, 0.f, 0.f);
        }
    }
    __syncthreads();

    {   // h1 = relu(C1ext @ [agg|..] + d1 + bvp1)
        int nl = tid >> 4, o = tid & 15;
        int nn = blockIdx.x * 16 + nl;
        float s = bvs[o] + d1[nn * 16 + o];
        const float4* c4 = (const float4*)(cs + o * 108);
        const float4* a4 = (const float4*)(aggs + nl * 108);
#pragma unroll
        for (int j = 0; j < 27; ++j) {
            float4 cv = c4[j], av = a4[j];
            s += cv.x * av.x + cv.y * av.y + cv.z * av.z + cv.w * av.w;
        }
        h1s[nl * 17 + o] = fmaxf(s, 0.f);
    }
    __syncthreads();

    {   // c2 = Ws2 @ h1 (bf16)
        int nl = tid >> 4, f = tid & 15;
        int nn = blockIdx.x * 16 + nl;
        const float* hr = h1s + nl * 17;
        float s = 0.f;
#pragma unroll
        for (int k = 0; k < 16; ++k) s += ws2[f * 17 + k] * hr[k];
        c2b[nn * 16 + f] = f2bf(s);
    }
    if (tid < 128) {   // d2 = P2 @ h1
        int nl = tid >> 3, o = tid & 7;
        int nn = blockIdx.x * 16 + nl;
        const float* hr = h1s + nl * 17;
        float s = 0.f;
#pragma unroll
        for (int k = 0; k < 16; ++k) s += p2s[o * 17 + k] * hr[k];
        d2[nn * 8 + o] = s;
    }
}

// ---------------------------------------------------------------------------
// agg2: 8 lanes/node, 32 nodes/block.  uint gathers, LDS-staged indices.
// ---------------------------------------------------------------------------
__global__ void __launch_bounds__(256) agg2(const unsigned int* __restrict__ c2u,
                                            const int* __restrict__ src,
                                            const float* __restrict__ d2,
                                            const float* __restrict__ C2p,
                                            const float* __restrict__ bvp2,
                                            float* __restrict__ h2) {
    __shared__ float cs[8 * 68];
    __shared__ float ag[32 * 68];
    __shared__ float bvs[8];
    __shared__ int idxs[512];
    int tid = threadIdx.x;
    for (int i = tid; i < 544; i += 256) cs[i] = C2p[i];
    if (tid < 8) bvs[tid] = bvp2[tid];
    idxs[tid] = src[blockIdx.x * 512 + tid];
    idxs[tid + 256] = src[blockIdx.x * 512 + 256 + tid];
    __syncthreads();

    int g = tid >> 3;           // 0..31
    int L = tid & 7;            // feats 2L, 2L+1
    {
        int id[K_DEG];
#pragma unroll
        for (int e = 0; e < K_DEG; ++e) id[e] = idxs[g * 16 + e];
        unsigned int v[K_DEG];
#pragma unroll
        for (int e = 0; e < K_DEG; ++e) v[e] = c2u[id[e] * 8 + L];
        float s0 = 0.f, q0 = 0.f, n0 = 1e30f, x0 = -1e30f;
        float s1 = 0.f, q1 = 0.f, n1 = 1e30f, x1 = -1e30f;
#pragma unroll
        for (int e = 0; e < K_DEG; ++e) {
            float a = bf2f((unsigned short)(v[e] & 0xffff));
            float b = bf2f((unsigned short)(v[e] >> 16));
            s0 += a; q0 += a * a; n0 = fminf(n0, a); x0 = fmaxf(x0, a);
            s1 += b; q1 += b * b; n1 = fminf(n1, b); x1 = fmaxf(x1, b);
        }
        float me0 = s0 * (1.f / 16.f), me1 = s1 * (1.f / 16.f);
        float sd0 = sqrtf(fmaxf(q0 * (1.f / 16.f) - me0 * me0, 0.f) + EPSV);
        float sd1 = sqrtf(fmaxf(q1 * (1.f / 16.f) - me1 * me1, 0.f) + EPSV);
        float* r = ag + g * 68 + 2 * L;
        *(float2*)(r)      = make_float2(me0, me1);
        *(float2*)(r + 16) = make_float2(n0, n1);
        *(float2*)(r + 32) = make_float2(x0, x1);
        *(float2*)(r + 48) = make_float2(sd0, sd1);
        if (L == 0) *(float4*)(ag + g * 68 + 64) = make_float4(0.f, 0.f, 0.f, 0.f);
    }
    __syncthreads();

    {
        int nl = tid >> 3, o = tid & 7;
        int nn = blockIdx.x * 32 + nl;
        float s = bvs[o] + d2[nn * 8 + o];
        const float4* c4 = (const float4*)(cs + o * 68);
        const float4* a4 = (const float4*)(ag + nl * 68);
#pragma unroll
        for (int j = 0; j < 17; ++j) {
            float4 cv = c4[j], av = a4[j];
            s += cv.x * av.x + cv.y * av.y + cv.z * av.z + cv.w * av.w;
        }
        h2[nn * 8 + o] = fmaxf(s, 0.f);
    }
}

// ---------------------------------------------------------------------------
// pool (50 contiguous nodes / graph) + fc + log_softmax.  1 wave per graph.
// ---------------------------------------------------------------------------
__global__ void pool_fc(const float* __restrict__ h2, const float* __restrict__ fc_w,
                        const float* __restrict__ fc_b, float* __restrict__ out) {
    int wave = threadIdx.x >> 6;
    int lane = threadIdx.x & 63;
    int g = blockIdx.x * 4 + wave;
    float s0 = 0.f, s1 = 0.f;
    if (lane < 50) {
        const float* hr = h2 + (g * 50 + lane) * 8;
        float v[8];
#pragma unroll
        for (int o = 0; o < 8; ++o) v[o] = hr[o];
#pragma unroll
        for (int o = 0; o < 8; ++o) { s0 += fc_w[o] * v[o]; s1 += fc_w[8 + o] * v[o]; }
    }
#pragma unroll
    for (int off = 32; off > 0; off >>= 1) {
        s0 += __shfl_down(s0, off);
        s1 += __shfl_down(s1, off);
    }
    if (lane == 0) {
        float l0 = s0 + fc_b[0], l1 = s1 + fc_b[1];
        float m = fmaxf(l0, l1);
        float lse = m + logf(expf(l0 - m) + expf(l1 - m));
        out[g * 2]     = l0 - lse;
        out[g * 2 + 1] = l1 - lse;
    }
}

extern "C" void kernel_launch(void* const* d_in, const int* in_sizes, int n_in,
                              void* d_out, int out_size, void* d_ws, size_t ws_size,
                              hipStream_t stream) {
    const float* x       = (const float*)d_in[0];
    const int*   eidx    = (const int*)d_in[1];   // [2][E]; row 0 = src
    const float* w1_pre  = (const float*)d_in[3];
    const float* b1_pre  = (const float*)d_in[4];
    const float* w1_post = (const float*)d_in[5];
    const float* b1_post = (const float*)d_in[6];
    const float* w1_lin  = (const float*)d_in[7];
    const float* b1_lin  = (const float*)d_in[8];
    const float* w2_pre  = (const float*)d_in[9];
    const float* b2_pre  = (const float*)d_in[10];
    const float* w2_post = (const float*)d_in[11];
    const float* b2_post = (const float*)d_in[12];
    const float* w2_lin  = (const float*)d_in[13];
    const float* b2_lin  = (const float*)d_in[14];
    const float* fc_w    = (const float*)d_in[15];
    const float* fc_b    = (const float*)d_in[16];
    float* out = (float*)d_out;
    const int* src = eidx;

    char* ws = (char*)d_ws;
    unsigned int*   c1u = (unsigned int*)ws;                  // N*16*4  = 12.8 MB
    unsigned short* c2b = (unsigned short*)(ws + 12800000);   // N*16*2  =  6.4 MB
    float* d1  = (float*)(ws + 19200000);                     // N*16*4  = 12.8 MB
    float* d2  = (float*)(ws + 32000000);                     // N*8*4   =  6.4 MB
    float* h2  = (float*)(ws + 38400000);                     // N*8*4   =  6.4 MB
    float* C1ext = (float*)(ws + 44800000);                   // 1728
    float* bvp1  = C1ext + 1728;                              // 16
    float* P1    = bvp1 + 16;                                 // 400
    float* C2p   = P1 + 400;                                  // 544
    float* bvp2  = C2p + 544;                                 // 8
    float* P2    = bvp2 + 8;                                  // 128

    prep<<<1, 256, 0, stream>>>(w1_pre, b1_pre, w1_post, b1_post, w1_lin, b1_lin,
                                w2_pre, b2_pre, w2_post, b2_post, w2_lin, b2_lin,
                                C1ext, bvp1, P1, C2p, bvp2, P2);
    pre1<<<(N_NODES + 255) / 256, 256, 0, stream>>>(x, w1_pre, P1, c1u, d1);
    agg1<<<N_NODES / 16, 256, 0, stream>>>(c1u, src, d1, C1ext, bvp1, w2_pre, P2, c2b, d2);
    agg2<<<N_NODES / 32, 256, 0, stream>>>((const unsigned int*)c2b, src, d2, C2p, bvp2, h2);
    pool_fc<<<G_GRAPHS / 4, 256, 0, stream>>>(h2, fc_w, fc_b, out);
}